// Round 7
// baseline (775.013 us; speedup 1.0000x reference)
//
#include <hip/hip_runtime.h>

#define T_LEN 512
#define OSTRIDE ((size_t)2048 * 512 * 32)  // elements per output copy

typedef float v2f __attribute__((ext_vector_type(2)));
#define PKFMA(a, b, c) __builtin_elementwise_fma((a), (b), (c))

__device__ __forceinline__ float rlf(float v, int l) {
  return __int_as_float(__builtin_amdgcn_readlane(__float_as_int(v), l));
}
// quad_perm broadcast of quad-lane sel (0..3): ctrl = sel * 0x55
#define QB(v, pat) __int_as_float(__builtin_amdgcn_mov_dpp(__float_as_int(v), (pat), 0xF, 0xF, false))

// ===========================================================================
// SINGLE fused kernel: prenet (chunked, wave-private LDS) + z-gate fold +
// encoder + decoder. Replaces the former setup/prenet/rec 3-dispatch chain.
//  - Each wave owns one batch element; NO __syncthreads (LDS wave-private,
//    same-wave DS ops are ordered).
//  - Phase A: 4 chunks x 128 rows (2 rows/lane), exact prenet FP order,
//    y2 -> LDS rows of stride 20 floats (80 B, 16-aligned).
//  - seq rows for chunk ch+1 are loaded into registers right after phase A
//    of chunk ch and pinned with sched_barrier(0) (r5-proven): their HBM
//    latency hides under the 128 encoder steps of chunk ch.
//  - Encoder: ds_read ring 4 rows ahead + 1-step zv pipeline (r6 structure).
//  - Wz/bz per-lane at start (replaces setup kernel, same FP order).
//  - xstart (y3) per-lane from LDS row 511 (replaces prenet branch).
// All arithmetic keeps identical operands/order -> bit-exact vs r6.
// ===========================================================================

#define ACTBODY()                                                           \
  do {                                                                      \
    float ee = __expf(g);                                                   \
    float rr = __builtin_amdgcn_rcpf(1.0f + ee);                            \
    float act = __builtin_fmaf(sa, rr, sb);                                 \
    float ii = QB(act, 0x00);                                               \
    float ff = QB(act, 0x55);                                               \
    float gg = QB(act, 0xAA);                                               \
    float oo = QB(act, 0xFF);                                               \
    c = __builtin_fmaf(ff, c, ii * gg);                                     \
    float th = __builtin_fmaf(                                              \
        -2.0f, __builtin_amdgcn_rcpf(1.0f + __expf(c + c)), 1.0f);          \
    h = oo * th;                                                            \
    _Pragma("unroll") for (int m = 0; m < 8; ++m) {                         \
      hk2[m].x = rlf(h, 8 * m);                                             \
      hk2[m].y = rlf(h, 8 * m + 4);                                         \
    }                                                                       \
  } while (0)

#define CELLZ(ZV)                                                           \
  do {                                                                      \
    v2f A, Bv;                                                              \
    A.x = (ZV); A.y = 0.f; Bv.x = 0.f; Bv.y = 0.f;                          \
    _Pragma("unroll") for (int m = 0; m < 8; m += 2) {                      \
      A = PKFMA(whh2[m], hk2[m], A);                                        \
      Bv = PKFMA(whh2[m + 1], hk2[m + 1], Bv);                              \
    }                                                                       \
    float g = (A.x + A.y) + (Bv.x + Bv.y);                                  \
    ACTBODY();                                                              \
  } while (0)

#define CELL(WX2, XA2, BB)                                                  \
  do {                                                                      \
    v2f A, Bv;                                                              \
    A.x = (BB); A.y = 0.f; Bv.x = 0.f; Bv.y = 0.f;                          \
    _Pragma("unroll") for (int m = 0; m < 8; m += 2) {                      \
      A = PKFMA(WX2[m], XA2[m], A);                                         \
      Bv = PKFMA(WX2[m + 1], XA2[m + 1], Bv);                               \
    }                                                                       \
    _Pragma("unroll") for (int m = 0; m < 8; m += 2) {                      \
      A = PKFMA(whh2[m], hk2[m], A);                                        \
      Bv = PKFMA(whh2[m + 1], hk2[m + 1], Bv);                              \
    }                                                                       \
    float g = (A.x + A.y) + (Bv.x + Bv.y);                                  \
    ACTBODY();                                                              \
  } while (0)

// z-gate GEMV from a y2 row (4 float4). Bit-exact replica of the original
// prenet phase-B order: A.x seeded with bz; A takes k={4q,4q+1},
// Bv takes k={4q+2,4q+3}; reduce (A.x+A.y)+(Bv.x+Bv.y).
#define ZGEMV(YQ, OUTV)                                                     \
  do {                                                                      \
    v2f A, Bv;                                                              \
    A.x = bz; A.y = 0.f; Bv.x = 0.f; Bv.y = 0.f;                            \
    _Pragma("unroll") for (int q = 0; q < 4; ++q) {                         \
      float4 v = (YQ)[q];                                                   \
      v2f ylo, yhi;                                                         \
      ylo.x = v.x; ylo.y = v.y; yhi.x = v.z; yhi.y = v.w;                   \
      A = PKFMA(wz2[2 * q + 0], ylo, A);                                    \
      Bv = PKFMA(wz2[2 * q + 1], yhi, Bv);                                  \
    }                                                                       \
    OUTV = (A.x + A.y) + (Bv.x + Bv.y);                                     \
  } while (0)

// phase A for one row held in 8 float4 regs (SR) -> y2 to LDS row ROWOFF.
// Exact prenet_y2_kernel FP order.
#define PHASEA_ROW(SR, ROWOFF)                                              \
  do {                                                                      \
    float in[32];                                                           \
    _Pragma("unroll") for (int q = 0; q < 8; ++q) {                         \
      in[q * 4 + 0] = SR[q].x;                                              \
      in[q * 4 + 1] = SR[q].y;                                              \
      in[q * 4 + 2] = SR[q].z;                                              \
      in[q * 4 + 3] = SR[q].w;                                              \
    }                                                                       \
    float y1[16];                                                           \
    _Pragma("unroll") for (int j = 0; j < 16; ++j) {                        \
      float a0 = b1[j], a1 = 0.f, a2 = 0.f, a3 = 0.f;                       \
      _Pragma("unroll") for (int k = 0; k < 32; k += 4) {                   \
        a0 = __builtin_fmaf(w1[j * 32 + k + 0], in[k + 0], a0);             \
        a1 = __builtin_fmaf(w1[j * 32 + k + 1], in[k + 1], a1);             \
        a2 = __builtin_fmaf(w1[j * 32 + k + 2], in[k + 2], a2);             \
        a3 = __builtin_fmaf(w1[j * 32 + k + 3], in[k + 3], a3);             \
      }                                                                     \
      float s = (a0 + a1) + (a2 + a3);                                      \
      y1[j] = s >= 0.f ? s : 0.01f * s;                                     \
    }                                                                       \
    float y2[16];                                                           \
    _Pragma("unroll") for (int j = 0; j < 16; ++j) {                        \
      float a0 = b2[j], a1 = 0.f, a2 = 0.f, a3 = 0.f;                       \
      _Pragma("unroll") for (int k = 0; k < 16; k += 4) {                   \
        a0 = __builtin_fmaf(w2[j * 16 + k + 0], y1[k + 0], a0);             \
        a1 = __builtin_fmaf(w2[j * 16 + k + 1], y1[k + 1], a1);             \
        a2 = __builtin_fmaf(w2[j * 16 + k + 2], y1[k + 2], a2);             \
        a3 = __builtin_fmaf(w2[j * 16 + k + 3], y1[k + 3], a3);             \
      }                                                                     \
      float s = (a0 + a1) + (a2 + a3);                                      \
      y2[j] = s >= 0.f ? s : 0.01f * s;                                     \
    }                                                                       \
    float* yp = myy + (ROWOFF) * 20;                                        \
    _Pragma("unroll") for (int q = 0; q < 4; ++q)                           \
      ((float4*)yp)[q] = make_float4(y2[q * 4 + 0], y2[q * 4 + 1],          \
                                     y2[q * 4 + 2], y2[q * 4 + 3]);         \
  } while (0)

#define LOADSEQ(DST, ROW)                                                   \
  do {                                                                      \
    const float4* sp4 = (const float4*)(sb0 + (size_t)(ROW) * 32);          \
    _Pragma("unroll") for (int q = 0; q < 8; ++q) DST[q] = sp4[q];          \
  } while (0)

__global__ __launch_bounds__(256, 2) void lstm_fused_kernel(
    const float* __restrict__ seq,
    const float* __restrict__ w1, const float* __restrict__ b1,
    const float* __restrict__ w2, const float* __restrict__ b2,
    const float* __restrict__ w3, const float* __restrict__ b3,
    const float* __restrict__ Wih, const float* __restrict__ Whh,
    const float* __restrict__ bih, const float* __restrict__ bhh,
    const float* __restrict__ hw1, const float* __restrict__ hb1,
    const float* __restrict__ hw2, const float* __restrict__ hb2,
    const float* __restrict__ pw, const float* __restrict__ pb,
    float* __restrict__ out) {
  __shared__ float y2s[4][128 * 20];  // 40960 B; wave-private regions
  const int lane = threadIdx.x & 63;
  const int wid = threadIdx.x >> 6;
  const int bu = __builtin_amdgcn_readfirstlane(blockIdx.x * 4 + wid);
  const int hr = lane >> 2;             // h index 0..15 (quad id)
  const int gi = (lane & 3) * 16 + hr;  // gate row 0..63
  const bool isT = (lane & 3) == 2;     // quad-lane 2 = g gate (tanh)

  const float sK = isT ? 2.0f : -1.0f;
  const float sa = isT ? -2.0f : 1.0f;
  const float sb = isT ? 1.0f : 0.0f;

  v2f whh2[8];
#pragma unroll
  for (int m = 0; m < 8; ++m) {
    whh2[m].x = Whh[gi * 16 + 2 * m + 0] * sK;
    whh2[m].y = Whh[gi * 16 + 2 * m + 1] * sK;
  }

  // ---- per-lane z-gate row (replaces setup_kernel; identical FP order) ----
  v2f wz2[8];
  float bz;
  {
    float acc[16];
#pragma unroll
    for (int k = 0; k < 16; ++k) acc[k] = 0.f;
    float bz0 = bih[gi] + bhh[gi];
#pragma unroll
    for (int j = 0; j < 16; ++j) {
      const float wij = Wih[gi * 16 + j];
#pragma unroll
      for (int k = 0; k < 16; ++k)
        acc[k] = __builtin_fmaf(wij, w3[j * 16 + k], acc[k]);
      bz0 = __builtin_fmaf(wij, b3[j], bz0);
    }
#pragma unroll
    for (int m = 0; m < 8; ++m) {
      wz2[m].x = sK * acc[2 * m + 0];
      wz2[m].y = sK * acc[2 * m + 1];
    }
    bz = sK * bz0;
  }

  float h = 0.f, c = 0.f;
  v2f hk2[8];
#pragma unroll
  for (int m = 0; m < 8; ++m) { hk2[m].x = 0.f; hk2[m].y = 0.f; }

  const float* sb0 = seq + ((size_t)bu * T_LEN) * 32;
  float* myy = &y2s[wid][0];

  // prologue: seq rows of chunk 0 (rows lane and lane+64), pinned early
  float4 sA[8], sB[8];
  LOADSEQ(sA, lane);
  LOADSEQ(sB, lane + 64);
  __builtin_amdgcn_sched_barrier(0);

  // ================= encoder: 4 chunks x 128 steps =================
  for (int ch = 0; ch < 4; ++ch) {
    // phase A for this chunk (uses sA/sB loaded one chunk earlier)
    PHASEA_ROW(sA, lane);
    PHASEA_ROW(sB, lane + 64);
    // prefetch next chunk's seq rows; latency hides under 128 enc steps
    if (ch < 3) {
      const int rbase = (ch + 1) * 128 + lane;
      LOADSEQ(sA, rbase);
      LOADSEQ(sB, rbase + 64);
    }
    __builtin_amdgcn_sched_barrier(0);

    // ring init: rows 0..3 of this chunk from LDS
    float4 yq[4][4];
#pragma unroll
    for (int u = 0; u < 4; ++u) {
#pragma unroll
      for (int q = 0; q < 4; ++q) yq[u][q] = ((float4*)(myy + u * 20))[q];
    }
    __builtin_amdgcn_sched_barrier(0);

    float zcur;
    ZGEMV(yq[0], zcur);  // row 0 of chunk

    for (int t0 = 0; t0 < 128; t0 += 4) {
#pragma unroll
      for (int u = 0; u < 4; ++u) {
        // znext (next row) is h-independent: same region as CELLZ so its
        // pkfmas fill the act-chain stall slots. Last znext of the chunk
        // reads a clamped duplicate of row 127 and is discarded.
        float znext;
        ZGEMV(yq[(u + 1) & 3], znext);
        CELLZ(zcur);
        int tn = t0 + u + 4;
        tn = tn < 128 ? tn : 127;  // tail reload of row 127, discarded
#pragma unroll
        for (int q = 0; q < 4; ++q)
          yq[u][q] = ((float4*)(myy + tn * 20))[q];
        // Pin issue order: refills may NOT sink past here (ring stays 4
        // rows ahead; waitcnt stays compiler-counted).
        __builtin_amdgcn_sched_barrier(0);
        zcur = znext;
      }
    }
  }

  // ---------------- decoder setup ----------------
  v2f wih2[8];
#pragma unroll
  for (int m = 0; m < 8; ++m) {
    wih2[m].x = Wih[gi * 16 + 2 * m + 0] * sK;
    wih2[m].y = Wih[gi * 16 + 2 * m + 1] * sK;
  }
  const float bias = (bih[gi] + bhh[gi]) * sK;

  const int mrow = (lane < 32) ? lane : (lane & 15);
  const float* msrc = (lane < 32) ? (pw + mrow * 16) : (hw1 + mrow * 16);
  const float mbias = (lane < 32) ? pb[mrow] : hb1[mrow];
  const float sl = (lane < 32) ? 1.0f : 0.01f;
  v2f mr2[8];
#pragma unroll
  for (int m = 0; m < 8; ++m) {
    mr2[m].x = msrc[2 * m + 0];
    mr2[m].y = msrc[2 * m + 1];
  }

  float Mr[16];
#pragma unroll
  for (int k = 0; k < 16; ++k) Mr[k] = 0.f;
#pragma unroll
  for (int j = 0; j < 16; ++j) {
    const float wj = (j & 1) ? wih2[j >> 1].y : wih2[j >> 1].x;
#pragma unroll
    for (int k = 0; k < 16; ++k)
      Mr[k] = __builtin_fmaf(wj, hw2[j * 16 + k], Mr[k]);
  }
  float mbias2 = bias;
#pragma unroll
  for (int j = 0; j < 16; ++j) {
    const float wj = (j & 1) ? wih2[j >> 1].y : wih2[j >> 1].x;
    mbias2 = __builtin_fmaf(wj, hb2[j], mbias2);
  }
  v2f Mr2[8];
#pragma unroll
  for (int m = 0; m < 8; ++m) {
    Mr2[m].x = Mr[2 * m + 0];
    Mr2[m].y = Mr[2 * m + 1];
  }

  // xstart = y3(row 511) computed per-lane from LDS row 127 of chunk 3
  // (exact prenet xstart FP order; same y2 bits -> same y3 bits).
  v2f xk2[8];
  {
    float yl[16];
#pragma unroll
    for (int q = 0; q < 4; ++q) {
      float4 v = ((float4*)(myy + 127 * 20))[q];
      yl[q * 4 + 0] = v.x;
      yl[q * 4 + 1] = v.y;
      yl[q * 4 + 2] = v.z;
      yl[q * 4 + 3] = v.w;
    }
    float y3[16];
#pragma unroll
    for (int j = 0; j < 16; ++j) {
      float a0 = b3[j], a1 = 0.f, a2 = 0.f, a3 = 0.f;
#pragma unroll
      for (int k = 0; k < 16; k += 4) {
        a0 = __builtin_fmaf(w3[j * 16 + k + 0], yl[k + 0], a0);
        a1 = __builtin_fmaf(w3[j * 16 + k + 1], yl[k + 1], a1);
        a2 = __builtin_fmaf(w3[j * 16 + k + 2], yl[k + 2], a2);
        a3 = __builtin_fmaf(w3[j * 16 + k + 3], yl[k + 3], a3);
      }
      y3[j] = (a0 + a1) + (a2 + a3);
    }
#pragma unroll
    for (int m = 0; m < 8; ++m) {
      xk2[m].x = y3[2 * m + 0];
      xk2[m].y = y3[2 * m + 1];
    }
  }

  const size_t obase = (size_t)bu * (T_LEN * 32) + (lane & 31);

  // ---------------- decoder: 512 steps ----------------
  CELL(wih2, xk2, bias);

  for (int t = 0; t < T_LEN; ++t) {
    v2f P, Q;
    P.x = mbias; P.y = 0.f; Q.x = 0.f; Q.y = 0.f;
#pragma unroll
    for (int m = 0; m < 8; m += 2) {
      P = PKFMA(mr2[m], hk2[m], P);
      Q = PKFMA(mr2[m + 1], hk2[m + 1], Q);
    }
    float y0 = (P.x + P.y) + (Q.x + Q.y);
    float yv = fmaxf(y0, y0 * sl);

    if (lane < 32) {
      const size_t off = obase + (size_t)(T_LEN - 1 - t) * 32;
      out[off] = yv;
      out[off + OSTRIDE] = yv;
    }

    if (t + 1 < T_LEN) {
      v2f uk2[8];
#pragma unroll
      for (int m = 0; m < 8; ++m) {
        uk2[m].x = rlf(yv, 32 + 2 * m + 0);
        uk2[m].y = rlf(yv, 32 + 2 * m + 1);
      }
      CELL(Mr2, uk2, mbias2);
    }
  }
}

extern "C" void kernel_launch(void* const* d_in, const int* in_sizes, int n_in,
                              void* d_out, int out_size, void* d_ws, size_t ws_size,
                              hipStream_t stream) {
  const float* seq = (const float*)d_in[0];
  const float* pre_w1 = (const float*)d_in[1];
  const float* pre_b1 = (const float*)d_in[2];
  const float* pre_w2 = (const float*)d_in[3];
  const float* pre_b2 = (const float*)d_in[4];
  const float* pre_w3 = (const float*)d_in[5];
  const float* pre_b3 = (const float*)d_in[6];
  const float* enc_Wih = (const float*)d_in[7];
  const float* enc_Whh = (const float*)d_in[8];
  const float* enc_bih = (const float*)d_in[9];
  const float* enc_bhh = (const float*)d_in[10];
  const float* h2l_w1 = (const float*)d_in[11];
  const float* h2l_b1 = (const float*)d_in[12];
  const float* h2l_w2 = (const float*)d_in[13];
  const float* h2l_b2 = (const float*)d_in[14];
  const float* post_w = (const float*)d_in[15];
  const float* post_b = (const float*)d_in[16];

  (void)d_ws;
  (void)ws_size;

  lstm_fused_kernel<<<dim3(512), dim3(256), 0, stream>>>(
      seq, pre_w1, pre_b1, pre_w2, pre_b2, pre_w3, pre_b3, enc_Wih, enc_Whh,
      enc_bih, enc_bhh, h2l_w1, h2l_b1, h2l_w2, h2l_b2, post_w, post_b,
      (float*)d_out);
}